// Round 1
// baseline (69.882 us; speedup 1.0000x reference)
//
#include <hip/hip_runtime.h>
#include <cstdint>
#include <cmath>

#define N_ROWS 8192
#define N_COLS 2048
#define OUT_SPIKES_ELEMS (N_ROWS * N_COLS)

__host__ __device__ inline uint32_t rotl32(uint32_t x, int d) {
  return (x << d) | (x >> (32 - d));
}

// Exact replication of JAX's threefry2x32 (20 rounds, 5 key injections).
__host__ __device__ inline void threefry2x32(uint32_t k0, uint32_t k1,
                                             uint32_t x0, uint32_t x1,
                                             uint32_t& o0, uint32_t& o1) {
  const uint32_t ks2 = k0 ^ k1 ^ 0x1BD11BDAu;
  x0 += k0; x1 += k1;
#define TFR(r) { x0 += x1; x1 = rotl32(x1, (r)); x1 ^= x0; }
  TFR(13) TFR(15) TFR(26) TFR(6)
  x0 += k1; x1 += ks2 + 1u;
  TFR(17) TFR(29) TFR(16) TFR(24)
  x0 += ks2; x1 += k0 + 2u;
  TFR(13) TFR(15) TFR(26) TFR(6)
  x0 += k0; x1 += k1 + 3u;
  TFR(17) TFR(29) TFR(16) TFR(24)
  x0 += k1; x1 += ks2 + 4u;
  TFR(13) TFR(15) TFR(26) TFR(6)
  x0 += ks2; x1 += k0 + 5u;
#undef TFR
  o0 = x0; o1 = x1;
}

// Partitionable-mode 32-bit random bits for flat index j (< 2^32): hi word of
// the 64-bit counter is 0; result is xor of the two threefry output words.
__device__ inline uint32_t random_bits32(uint32_t k0, uint32_t k1, uint32_t j) {
  uint32_t o0, o1;
  threefry2x32(k0, k1, 0u, j, o0, o1);
  return o0 ^ o1;
}

// bits -> [0,1) float exactly as jax.random.uniform does
__device__ inline float unit_from_bits(uint32_t bits) {
  return __uint_as_float((bits >> 9) | 0x3f800000u) - 1.0f;  // exact subtract
}

// XLA's ErfInv32 expansion (Giles polynomial), non-contracted f32 ops.
__device__ inline float xla_erfinv(float x) {
  float w = -log1pf(__fmul_rn(-x, x));
  float p;
  if (w < 5.0f) {
    w = __fadd_rn(w, -2.5f);
    p = 2.81022636e-08f;
    p = __fadd_rn(3.43273939e-07f,  __fmul_rn(p, w));
    p = __fadd_rn(-3.5233877e-06f,  __fmul_rn(p, w));
    p = __fadd_rn(-4.39150654e-06f, __fmul_rn(p, w));
    p = __fadd_rn(0.00021858087f,   __fmul_rn(p, w));
    p = __fadd_rn(-0.00125372503f,  __fmul_rn(p, w));
    p = __fadd_rn(-0.00417768164f,  __fmul_rn(p, w));
    p = __fadd_rn(0.246640727f,     __fmul_rn(p, w));
    p = __fadd_rn(1.50140941f,      __fmul_rn(p, w));
  } else {
    w = __fadd_rn(sqrtf(w), -3.0f);
    p = -0.000200214257f;
    p = __fadd_rn(0.000100950558f,  __fmul_rn(p, w));
    p = __fadd_rn(0.00134934322f,   __fmul_rn(p, w));
    p = __fadd_rn(-0.00367342844f,  __fmul_rn(p, w));
    p = __fadd_rn(0.00573950773f,   __fmul_rn(p, w));
    p = __fadd_rn(-0.0076224613f,   __fmul_rn(p, w));
    p = __fadd_rn(0.00943887047f,   __fmul_rn(p, w));
    p = __fadd_rn(1.00167406f,      __fmul_rn(p, w));
    p = __fadd_rn(2.83297682f,      __fmul_rn(p, w));
  }
  return __fmul_rn(p, x);
}

// jax.random.normal f32: u = max(lo, unit*2 + lo), lo = nextafter(-1,0);
// return f32(sqrt(2)) * erfinv(u)
__device__ inline float normal_from_bits(uint32_t bits) {
  const float lo = -0.99999994f;  // 0xBF7FFFFF
  float unit = unit_from_bits(bits);
  float t = __fadd_rn(__fmul_rn(unit, 2.0f), lo);
  t = fmaxf(lo, t);
  return __fmul_rn(1.4142135623730951f, xla_erfinv(t));
}

// gumbel = -log(-log(uniform(tiny, 1)))
__device__ inline float gumbel_from_bits(uint32_t bits) {
  const float tiny = 1.17549435e-38f;  // np.finfo(f32).tiny
  float u = unit_from_bits(bits);
  float t = __fadd_rn(__fmul_rn(u, 1.0f), tiny);  // span (1 - tiny) rounds to 1.0f
  t = fmaxf(tiny, t);
  return -logf(-logf(t));
}

__global__ __launch_bounds__(256) void spike_kernel(
    const float* __restrict__ inputs, const float* __restrict__ inhibition,
    float* __restrict__ out, float csig,
    uint32_t kn0, uint32_t kn1, uint32_t ku0, uint32_t ku1,
    uint32_t kc0, uint32_t kc1) {
  const int row = blockIdx.x;
  const int tid = threadIdx.x;

  // --- inhibition Euler-Maruyama update (all threads compute redundantly) ---
  float nrm = normal_from_bits(random_bits32(kn0, kn1, (uint32_t)row));
  const float cdecay = 0.9f;  // f32(1.0 - 100.0*0.001)
  float ih = __fadd_rn(__fmul_rn(cdecay, inhibition[row]), __fmul_rn(csig, nrm));

  // --- per-thread partial sum(exp) and argmax(logit + gumbel) ---
  float vmax = -INFINITY;
  int   imax = 0;
  double tsum = 0.0;
  const float* rowp = inputs + (size_t)row * N_COLS;

#pragma unroll
  for (int ch = 0; ch < 2; ++ch) {
    const int col = 4 * tid + 1024 * ch;
    float4 in4 = *reinterpret_cast<const float4*>(rowp + col);
    float xv[4] = {in4.x, in4.y, in4.z, in4.w};
#pragma unroll
    for (int k = 0; k < 4; ++k) {
      const uint32_t j = (uint32_t)(row * N_COLS + col + k);
      float g = gumbel_from_bits(random_bits32(kc0, kc1, j));
      float x = __fsub_rn(xv[k], ih);   // == log(clip(exp(x))) to ~1 ulp
      tsum += (double)expf(x);
      float v = __fadd_rn(g, x);
      int idx = col + k;
      if (v > vmax || (v == vmax && idx < imax)) { vmax = v; imax = idx; }
    }
  }

  // --- wave (64-lane) reduction ---
  for (int off = 32; off > 0; off >>= 1) {
    double os = __shfl_down(tsum, off);
    float  ov = __shfl_down(vmax, off);
    int    oi = __shfl_down(imax, off);
    tsum += os;
    if (ov > vmax || (ov == vmax && oi < imax)) { vmax = ov; imax = oi; }
  }

  // --- cross-wave reduction in LDS ---
  __shared__ double s_sum[4];
  __shared__ float  s_v[4];
  __shared__ int    s_i[4];
  __shared__ int    s_final[2];  // [argmax col, spike flag]
  const int wid = tid >> 6;
  if ((tid & 63) == 0) { s_sum[wid] = tsum; s_v[wid] = vmax; s_i[wid] = imax; }
  __syncthreads();

  if (tid == 0) {
    double total = s_sum[0] + s_sum[1] + s_sum[2] + s_sum[3];
    float bv = s_v[0];
    int   bi = s_i[0];
    for (int w = 1; w < 4; ++w) {
      if (s_v[w] > bv || (s_v[w] == bv && s_i[w] < bi)) { bv = s_v[w]; bi = s_i[w]; }
    }
    // spike_occurred = uniform(ku)[row] < DT * total_rate
    float urand = unit_from_bits(random_bits32(ku0, ku1, (uint32_t)row));
    float thr = __fmul_rn(0.001f, (float)total);
    int spike = (urand < thr) ? 1 : 0;
    s_final[0] = bi;
    s_final[1] = spike;
    // inhib_out = inhib + max(out_spikes)*5
    out[OUT_SPIKES_ELEMS + row] = spike ? __fadd_rn(ih, 5.0f) : __fadd_rn(ih, 0.0f);
  }
  __syncthreads();

  const int bi = s_final[0];
  const int spike = s_final[1];
  float* orow = out + (size_t)row * N_COLS;
#pragma unroll
  for (int ch = 0; ch < 2; ++ch) {
    const int col = 4 * tid + 1024 * ch;
    float4 z = make_float4(0.f, 0.f, 0.f, 0.f);
    if (spike && bi >= col && bi < col + 4) {
      (&z.x)[bi - col] = 1.0f;
    }
    *reinterpret_cast<float4*>(orow + col) = z;
  }
}

extern "C" void kernel_launch(void* const* d_in, const int* in_sizes, int n_in,
                              void* d_out, int out_size, void* d_ws, size_t ws_size,
                              hipStream_t stream) {
  const float* inputs     = (const float*)d_in[0];
  const float* inhibition = (const float*)d_in[1];
  float* out = (float*)d_out;

  // key = jax.random.key(42) -> (0, 42); partitionable fold-like split into 3:
  // k_i = threefry2x32(key, (0, i)), both output words.
  uint32_t kn0, kn1, ku0, ku1, kc0, kc1;
  threefry2x32(0u, 42u, 0u, 0u, kn0, kn1);
  threefry2x32(0u, 42u, 0u, 1u, ku0, ku1);
  threefry2x32(0u, 42u, 0u, 2u, kc0, kc1);

  // f32(DECAY_SIGMA * DT_SQRT): host double sqrt matches np.sqrt bit-exactly
  const float csig = (float)(5.0 * sqrt(0.001));

  dim3 grid(N_ROWS), block(256);
  hipLaunchKernelGGL(spike_kernel, grid, block, 0, stream,
                     inputs, inhibition, out, csig,
                     kn0, kn1, ku0, ku1, kc0, kc1);
}

// Round 2
// 67.288 us; speedup vs baseline: 1.0386x; 1.0386x over previous
//
#include <hip/hip_runtime.h>
#include <cstdint>
#include <cmath>

#define N_ROWS 8192
#define N_COLS 2048
#define OUT_SPIKES_ELEMS (N_ROWS * N_COLS)

__host__ __device__ inline uint32_t rotl32(uint32_t x, int d) {
  return (x << d) | (x >> (32 - d));
}

// Exact replication of JAX's threefry2x32 (20 rounds, 5 key injections).
__host__ __device__ inline void threefry2x32(uint32_t k0, uint32_t k1,
                                             uint32_t x0, uint32_t x1,
                                             uint32_t& o0, uint32_t& o1) {
  const uint32_t ks2 = k0 ^ k1 ^ 0x1BD11BDAu;
  x0 += k0; x1 += k1;
#define TFR(r) { x0 += x1; x1 = rotl32(x1, (r)); x1 ^= x0; }
  TFR(13) TFR(15) TFR(26) TFR(6)
  x0 += k1; x1 += ks2 + 1u;
  TFR(17) TFR(29) TFR(16) TFR(24)
  x0 += ks2; x1 += k0 + 2u;
  TFR(13) TFR(15) TFR(26) TFR(6)
  x0 += k0; x1 += k1 + 3u;
  TFR(17) TFR(29) TFR(16) TFR(24)
  x0 += k1; x1 += ks2 + 4u;
  TFR(13) TFR(15) TFR(26) TFR(6)
  x0 += ks2; x1 += k0 + 5u;
#undef TFR
  o0 = x0; o1 = x1;
}

// Partitionable-mode 32-bit random bits for flat index j (< 2^32).
__device__ inline uint32_t random_bits32(uint32_t k0, uint32_t k1, uint32_t j) {
  uint32_t o0, o1;
  threefry2x32(k0, k1, 0u, j, o0, o1);
  return o0 ^ o1;
}

// bits -> [0,1) float exactly as jax.random.uniform does
__device__ inline float unit_from_bits(uint32_t bits) {
  return __uint_as_float((bits >> 9) | 0x3f800000u) - 1.0f;
}

// XLA's ErfInv32 expansion (Giles polynomial), non-contracted f32 ops.
__device__ inline float xla_erfinv(float x) {
  float w = -log1pf(__fmul_rn(-x, x));
  float p;
  if (w < 5.0f) {
    w = __fadd_rn(w, -2.5f);
    p = 2.81022636e-08f;
    p = __fadd_rn(3.43273939e-07f,  __fmul_rn(p, w));
    p = __fadd_rn(-3.5233877e-06f,  __fmul_rn(p, w));
    p = __fadd_rn(-4.39150654e-06f, __fmul_rn(p, w));
    p = __fadd_rn(0.00021858087f,   __fmul_rn(p, w));
    p = __fadd_rn(-0.00125372503f,  __fmul_rn(p, w));
    p = __fadd_rn(-0.00417768164f,  __fmul_rn(p, w));
    p = __fadd_rn(0.246640727f,     __fmul_rn(p, w));
    p = __fadd_rn(1.50140941f,      __fmul_rn(p, w));
  } else {
    w = __fadd_rn(sqrtf(w), -3.0f);
    p = -0.000200214257f;
    p = __fadd_rn(0.000100950558f,  __fmul_rn(p, w));
    p = __fadd_rn(0.00134934322f,   __fmul_rn(p, w));
    p = __fadd_rn(-0.00367342844f,  __fmul_rn(p, w));
    p = __fadd_rn(0.00573950773f,   __fmul_rn(p, w));
    p = __fadd_rn(-0.0076224613f,   __fmul_rn(p, w));
    p = __fadd_rn(0.00943887047f,   __fmul_rn(p, w));
    p = __fadd_rn(1.00167406f,      __fmul_rn(p, w));
    p = __fadd_rn(2.83297682f,      __fmul_rn(p, w));
  }
  return __fmul_rn(p, x);
}

__device__ inline float normal_from_bits(uint32_t bits) {
  const float lo = -0.99999994f;  // nextafter(-1,0)
  float unit = unit_from_bits(bits);
  float t = __fadd_rn(__fmul_rn(unit, 2.0f), lo);
  t = fmaxf(lo, t);
  return __fmul_rn(1.4142135623730951f, xla_erfinv(t));
}

// EXACT gumbel tail (ocml logf) — identical float path to the round-1 kernel.
// t must already be the clamped uniform argument (>= tiny).
__device__ inline float gumbel_exact_from_t(float t) {
  return -logf(-logf(t));
}

__global__ __launch_bounds__(256) void spike_kernel(
    const float* __restrict__ inputs, const float* __restrict__ inhibition,
    float* __restrict__ out, float csig,
    uint32_t kn0, uint32_t kn1, uint32_t ku0, uint32_t ku1,
    uint32_t kc0, uint32_t kc1) {
  const int row = blockIdx.x;
  const int tid = threadIdx.x;
  const float tiny = 1.17549435e-38f;
  const float ln2 = 0.69314718055994531f;

  // --- inhibition Euler-Maruyama update (redundant per-thread, cheap) ---
  float nrm = normal_from_bits(random_bits32(kn0, kn1, (uint32_t)row));
  const float cdecay = 0.9f;
  float ih = __fadd_rn(__fmul_rn(cdecay, inhibition[row]), __fmul_rn(csig, nrm));

  // --- phase A: fast gumbel, track max only; exact exp-sum (round-1 path) ---
  float tbuf[8];   // clamped uniform args (for exact recompute)
  float xbuf[8];   // x = input - ih
  float vhat[8];   // fast gumbel + x
  float vmax = -INFINITY;
  double tsum = 0.0;
  const float* rowp = inputs + (size_t)row * N_COLS;

#pragma unroll
  for (int ch = 0; ch < 2; ++ch) {
    const int col = 4 * tid + 1024 * ch;
    float4 in4 = *reinterpret_cast<const float4*>(rowp + col);
    float xv[4] = {in4.x, in4.y, in4.z, in4.w};
#pragma unroll
    for (int k = 0; k < 4; ++k) {
      const int i8 = 4 * ch + k;
      const uint32_t j = (uint32_t)(row * N_COLS + col + k);
      uint32_t bits = random_bits32(kc0, kc1, j);
      float u = unit_from_bits(bits);
      float t = __fadd_rn(u, tiny);  // == fmax(tiny, u*1+tiny): u>=0
      // fast gumbel: 2x v_log_f32 + 2 muls; |fast-exact| <= ~1e-5
      float w = __fmul_rn(-ln2, __log2f(t));
      float g = __fmul_rn(-ln2, __log2f(w));
      float x = __fsub_rn(xv[k], ih);
      float v = __fadd_rn(g, x);
      tbuf[i8] = t; xbuf[i8] = x; vhat[i8] = v;
      vmax = fmaxf(vmax, v);
      tsum += (double)expf(x);  // identical to round-1 sum path
    }
  }

  // --- wave reduce: max(vhat) and sum ---
  for (int off = 32; off > 0; off >>= 1) {
    tsum += __shfl_down(tsum, off);
    vmax = fmaxf(vmax, __shfl_down(vmax, off));
  }

  __shared__ double s_sum[4];
  __shared__ float  s_v[4];
  __shared__ float  s_cv[4];
  __shared__ int    s_ci[4];
  __shared__ int    s_final[2];
  const int wid = tid >> 6;
  if ((tid & 63) == 0) { s_sum[wid] = tsum; s_v[wid] = vmax; }
  __syncthreads();

  // all threads compute block max M
  float M = fmaxf(fmaxf(s_v[0], s_v[1]), fmaxf(s_v[2], s_v[3]));
  const float thrM = __fsub_rn(M, 1e-3f);  // margin >> fast-gumbel error

  // --- phase B: exact (ocml) gumbel only for candidates near the max ---
  float cval = -INFINITY;
  int   cidx = 0x7fffffff;
  bool any = false;
#pragma unroll
  for (int i8 = 0; i8 < 8; ++i8) any = any || (vhat[i8] >= thrM);
  if (any) {
#pragma unroll
    for (int i8 = 0; i8 < 8; ++i8) {
      if (vhat[i8] >= thrM) {
        float g = gumbel_exact_from_t(tbuf[i8]);
        float v = __fadd_rn(g, xbuf[i8]);  // bit-identical to round-1 values
        int idx = 4 * tid + 1024 * (i8 >> 2) + (i8 & 3);
        if (v > cval || (v == cval && idx < cidx)) { cval = v; cidx = idx; }
      }
    }
  }

  // wave reduce argmax (lexicographic, first-max-wins like jnp.argmax)
  for (int off = 32; off > 0; off >>= 1) {
    float ov = __shfl_down(cval, off);
    int   oi = __shfl_down(cidx, off);
    if (ov > cval || (ov == cval && oi < cidx)) { cval = ov; cidx = oi; }
  }
  if ((tid & 63) == 0) { s_cv[wid] = cval; s_ci[wid] = cidx; }
  __syncthreads();

  if (tid == 0) {
    double total = s_sum[0] + s_sum[1] + s_sum[2] + s_sum[3];
    float bv = s_cv[0];
    int   bi = s_ci[0];
    for (int w = 1; w < 4; ++w) {
      if (s_cv[w] > bv || (s_cv[w] == bv && s_ci[w] < bi)) { bv = s_cv[w]; bi = s_ci[w]; }
    }
    float urand = unit_from_bits(random_bits32(ku0, ku1, (uint32_t)row));
    float thr = __fmul_rn(0.001f, (float)total);
    int spike = (urand < thr) ? 1 : 0;
    s_final[0] = bi;
    s_final[1] = spike;
    out[OUT_SPIKES_ELEMS + row] = spike ? __fadd_rn(ih, 5.0f) : __fadd_rn(ih, 0.0f);
  }
  __syncthreads();

  const int bi = s_final[0];
  const int spike = s_final[1];
  float* orow = out + (size_t)row * N_COLS;
#pragma unroll
  for (int ch = 0; ch < 2; ++ch) {
    const int col = 4 * tid + 1024 * ch;
    float4 z = make_float4(0.f, 0.f, 0.f, 0.f);
    if (spike && bi >= col && bi < col + 4) {
      (&z.x)[bi - col] = 1.0f;
    }
    *reinterpret_cast<float4*>(orow + col) = z;
  }
}

extern "C" void kernel_launch(void* const* d_in, const int* in_sizes, int n_in,
                              void* d_out, int out_size, void* d_ws, size_t ws_size,
                              hipStream_t stream) {
  const float* inputs     = (const float*)d_in[0];
  const float* inhibition = (const float*)d_in[1];
  float* out = (float*)d_out;

  uint32_t kn0, kn1, ku0, ku1, kc0, kc1;
  threefry2x32(0u, 42u, 0u, 0u, kn0, kn1);
  threefry2x32(0u, 42u, 0u, 1u, ku0, ku1);
  threefry2x32(0u, 42u, 0u, 2u, kc0, kc1);

  const float csig = (float)(5.0 * sqrt(0.001));

  dim3 grid(N_ROWS), block(256);
  hipLaunchKernelGGL(spike_kernel, grid, block, 0, stream,
                     inputs, inhibition, out, csig,
                     kn0, kn1, ku0, ku1, kc0, kc1);
}

// Round 8
// 64.029 us; speedup vs baseline: 1.0914x; 1.0509x over previous
//
#include <hip/hip_runtime.h>
#include <cstdint>
#include <cmath>

#define N_ROWS 8192
#define N_COLS 2048
#define OUT_SPIKES_ELEMS (N_ROWS * N_COLS)

__host__ __device__ inline uint32_t rotl32(uint32_t x, int d) {
#if defined(__HIP_DEVICE_COMPILE__)
  return __builtin_amdgcn_alignbit(x, x, 32u - (uint32_t)d);  // v_alignbit_b32
#else
  return (x << d) | (x >> (32 - d));
#endif
}

// Exact replication of JAX's threefry2x32 (20 rounds, 5 key injections).
__host__ __device__ inline void threefry2x32(uint32_t k0, uint32_t k1,
                                             uint32_t x0, uint32_t x1,
                                             uint32_t& o0, uint32_t& o1) {
  const uint32_t ks2 = k0 ^ k1 ^ 0x1BD11BDAu;
  x0 += k0; x1 += k1;
#define TFR(r) { x0 += x1; x1 = rotl32(x1, (r)); x1 ^= x0; }
  TFR(13) TFR(15) TFR(26) TFR(6)
  x0 += k1; x1 += ks2 + 1u;
  TFR(17) TFR(29) TFR(16) TFR(24)
  x0 += ks2; x1 += k0 + 2u;
  TFR(13) TFR(15) TFR(26) TFR(6)
  x0 += k0; x1 += k1 + 3u;
  TFR(17) TFR(29) TFR(16) TFR(24)
  x0 += k1; x1 += ks2 + 4u;
  TFR(13) TFR(15) TFR(26) TFR(6)
  x0 += ks2; x1 += k0 + 5u;
#undef TFR
  o0 = x0; o1 = x1;
}

__device__ inline uint32_t random_bits32(uint32_t k0, uint32_t k1, uint32_t j) {
  uint32_t o0, o1;
  threefry2x32(k0, k1, 0u, j, o0, o1);
  return o0 ^ o1;
}

// bits -> [0,1) float exactly as jax.random.uniform does
__device__ inline float unit_from_bits(uint32_t bits) {
  return __uint_as_float((bits >> 9) | 0x3f800000u) - 1.0f;
}

// XLA's ErfInv32 expansion (Giles polynomial), non-contracted f32 ops.
__device__ inline float xla_erfinv(float x) {
  float w = -log1pf(__fmul_rn(-x, x));
  float p;
  if (w < 5.0f) {
    w = __fadd_rn(w, -2.5f);
    p = 2.81022636e-08f;
    p = __fadd_rn(3.43273939e-07f,  __fmul_rn(p, w));
    p = __fadd_rn(-3.5233877e-06f,  __fmul_rn(p, w));
    p = __fadd_rn(-4.39150654e-06f, __fmul_rn(p, w));
    p = __fadd_rn(0.00021858087f,   __fmul_rn(p, w));
    p = __fadd_rn(-0.00125372503f,  __fmul_rn(p, w));
    p = __fadd_rn(-0.00417768164f,  __fmul_rn(p, w));
    p = __fadd_rn(0.246640727f,     __fmul_rn(p, w));
    p = __fadd_rn(1.50140941f,      __fmul_rn(p, w));
  } else {
    w = __fadd_rn(sqrtf(w), -3.0f);
    p = -0.000200214257f;
    p = __fadd_rn(0.000100950558f,  __fmul_rn(p, w));
    p = __fadd_rn(0.00134934322f,   __fmul_rn(p, w));
    p = __fadd_rn(-0.00367342844f,  __fmul_rn(p, w));
    p = __fadd_rn(0.00573950773f,   __fmul_rn(p, w));
    p = __fadd_rn(-0.0076224613f,   __fmul_rn(p, w));
    p = __fadd_rn(0.00943887047f,   __fmul_rn(p, w));
    p = __fadd_rn(1.00167406f,      __fmul_rn(p, w));
    p = __fadd_rn(2.83297682f,      __fmul_rn(p, w));
  }
  return __fmul_rn(p, x);
}

__device__ inline float normal_from_bits(uint32_t bits) {
  const float lo = -0.99999994f;  // nextafter(-1,0)
  float unit = unit_from_bits(bits);
  float t = __fadd_rn(__fmul_rn(unit, 2.0f), lo);
  t = fmaxf(lo, t);
  return __fmul_rn(1.4142135623730951f, xla_erfinv(t));
}

__global__ __launch_bounds__(256, 4) void spike_kernel(
    const float* __restrict__ inputs, const float* __restrict__ inhibition,
    float* __restrict__ out, float csig,
    uint32_t kn0, uint32_t kn1, uint32_t ku0, uint32_t ku1,
    uint32_t kc0, uint32_t kc1) {
  const int row = blockIdx.x;
  const int tid = threadIdx.x;
  const int wid = tid >> 6;
  const float tiny = 1.17549435e-38f;
  const float ln2 = 0.69314718055994531f;
  const float log2e = 1.4426950408889634f;

  // --- inhibition Euler-Maruyama update (exact, redundant per-thread) ---
  float nrm = normal_from_bits(random_bits32(kn0, kn1, (uint32_t)row));
  const float cdecay = 0.9f;
  float ih = __fadd_rn(__fmul_rn(cdecay, inhibition[row]), __fmul_rn(csig, nrm));

  // --- issue both global loads before compute ---
  const float* rowp = inputs + (size_t)row * N_COLS;
  const float4* rowp4 = reinterpret_cast<const float4*>(rowp);
  float4 a0 = rowp4[tid];
  float4 a1 = rowp4[tid + 256];

  // --- phase A: fast gumbel, wave max; fast-exp sum in double ---
  uint32_t bits8[8];
  float vhat[8];
  float vmax = -INFINITY;
  double tsum = 0.0;
  const uint32_t jbase = (uint32_t)(row * N_COLS + 4 * tid);
  float xv[8] = {a0.x, a0.y, a0.z, a0.w, a1.x, a1.y, a1.z, a1.w};

#pragma unroll
  for (int i8 = 0; i8 < 8; ++i8) {
    const uint32_t j = jbase + (uint32_t)((i8 & 3) + 1024 * (i8 >> 2));
    uint32_t bits = random_bits32(kc0, kc1, j);
    float u = unit_from_bits(bits);
    float t = __fadd_rn(u, tiny);
    // fast gumbel: 2x v_log_f32 + 2 muls; |fast-exact| <= ~2e-5
    float w = __fmul_rn(-ln2, __log2f(t));
    float g = __fmul_rn(-ln2, __log2f(w));
    float x = __fsub_rn(xv[i8], ih);
    float v = __fadd_rn(g, x);
    bits8[i8] = bits; vhat[i8] = v;
    vmax = fmaxf(vmax, v);
    // fast exp: v_mul + v_exp_f32 (rel err ~2e-7; flip risk analyzed ~1e-3)
    tsum += (double)__builtin_amdgcn_exp2f(__fmul_rn(x, log2e));
  }

  // --- wave butterfly reduce (all lanes get result) ---
#pragma unroll
  for (int off = 32; off > 0; off >>= 1) {
    tsum += __shfl_xor(tsum, off);
    vmax = fmaxf(vmax, __shfl_xor(vmax, off));
  }
  const float thrM = __fsub_rn(vmax, 1e-3f);  // per-WAVE margin

  // --- phase B: exact ocml gumbel only for near-max candidates (~1/row) ---
  float cval = -INFINITY;
  int   cidx = 0x7fffffff;
#pragma unroll
  for (int i8 = 0; i8 < 8; ++i8) {
    if (vhat[i8] >= thrM) {
      int col = 4 * tid + 1024 * (i8 >> 2) + (i8 & 3);
      float t = __fadd_rn(unit_from_bits(bits8[i8]), tiny);
      float g = -logf(-logf(t));                 // exact round-1 float path
      float x = __fsub_rn(rowp[col], ih);        // reload input (L1/L2 hot)
      float v = __fadd_rn(g, x);
      if (v > cval || (v == cval && col < cidx)) { cval = v; cidx = col; }
    }
  }

  // wave butterfly lex-argmax of exact candidates
#pragma unroll
  for (int off = 32; off > 0; off >>= 1) {
    float ov = __shfl_xor(cval, off);
    int   oi = __shfl_xor(cidx, off);
    if (ov > cval || (ov == cval && oi < cidx)) { cval = ov; cidx = oi; }
  }

  // --- single cross-wave combine ---
  __shared__ double s_sum[4];
  __shared__ float  s_cv[4];
  __shared__ int    s_ci[4];
  __shared__ int    s_final[2];
  if ((tid & 63) == 0) { s_sum[wid] = tsum; s_cv[wid] = cval; s_ci[wid] = cidx; }
  __syncthreads();

  if (tid == 0) {
    double total = s_sum[0] + s_sum[1] + s_sum[2] + s_sum[3];
    float bv = s_cv[0];
    int   bi = s_ci[0];
    for (int w = 1; w < 4; ++w) {
      if (s_cv[w] > bv || (s_cv[w] == bv && s_ci[w] < bi)) { bv = s_cv[w]; bi = s_ci[w]; }
    }
    float urand = unit_from_bits(random_bits32(ku0, ku1, (uint32_t)row));
    float thr = __fmul_rn(0.001f, (float)total);
    int spike = (urand < thr) ? 1 : 0;
    s_final[0] = bi;
    s_final[1] = spike;
    out[OUT_SPIKES_ELEMS + row] = spike ? __fadd_rn(ih, 5.0f) : ih;
  }
  __syncthreads();

  const int bi = s_final[0];
  const int spike = s_final[1];
  float* orow = out + (size_t)row * N_COLS;
#pragma unroll
  for (int ch = 0; ch < 2; ++ch) {
    const int col = 4 * tid + 1024 * ch;
    float4 z = make_float4(0.f, 0.f, 0.f, 0.f);
    if (spike && bi >= col && bi < col + 4) {
      (&z.x)[bi - col] = 1.0f;
    }
    *reinterpret_cast<float4*>(orow + col) = z;
  }
}

extern "C" void kernel_launch(void* const* d_in, const int* in_sizes, int n_in,
                              void* d_out, int out_size, void* d_ws, size_t ws_size,
                              hipStream_t stream) {
  const float* inputs     = (const float*)d_in[0];
  const float* inhibition = (const float*)d_in[1];
  float* out = (float*)d_out;

  uint32_t kn0, kn1, ku0, ku1, kc0, kc1;
  threefry2x32(0u, 42u, 0u, 0u, kn0, kn1);
  threefry2x32(0u, 42u, 0u, 1u, ku0, ku1);
  threefry2x32(0u, 42u, 0u, 2u, kc0, kc1);

  const float csig = (float)(5.0 * sqrt(0.001));

  dim3 grid(N_ROWS), block(256);
  hipLaunchKernelGGL(spike_kernel, grid, block, 0, stream,
                     inputs, inhibition, out, csig,
                     kn0, kn1, ku0, ku1, kc0, kc1);
}

// Round 9
// 58.092 us; speedup vs baseline: 1.2030x; 1.1022x over previous
//
#include <hip/hip_runtime.h>
#include <cstdint>
#include <cmath>

#define N_ROWS 8192
#define N_COLS 2048
#define OUT_SPIKES_ELEMS (N_ROWS * N_COLS)

__host__ __device__ inline uint32_t rotl32(uint32_t x, int d) {
#if defined(__HIP_DEVICE_COMPILE__)
  return __builtin_amdgcn_alignbit(x, x, 32u - (uint32_t)d);  // v_alignbit_b32
#else
  return (x << d) | (x >> (32 - d));
#endif
}

// Exact replication of JAX's threefry2x32 (20 rounds, 5 key injections).
__host__ __device__ inline void threefry2x32(uint32_t k0, uint32_t k1,
                                             uint32_t x0, uint32_t x1,
                                             uint32_t& o0, uint32_t& o1) {
  const uint32_t ks2 = k0 ^ k1 ^ 0x1BD11BDAu;
  x0 += k0; x1 += k1;
#define TFR(r) { x0 += x1; x1 = rotl32(x1, (r)); x1 ^= x0; }
  TFR(13) TFR(15) TFR(26) TFR(6)
  x0 += k1; x1 += ks2 + 1u;
  TFR(17) TFR(29) TFR(16) TFR(24)
  x0 += ks2; x1 += k0 + 2u;
  TFR(13) TFR(15) TFR(26) TFR(6)
  x0 += k0; x1 += k1 + 3u;
  TFR(17) TFR(29) TFR(16) TFR(24)
  x0 += k1; x1 += ks2 + 4u;
  TFR(13) TFR(15) TFR(26) TFR(6)
  x0 += ks2; x1 += k0 + 5u;
#undef TFR
  o0 = x0; o1 = x1;
}

__device__ inline uint32_t random_bits32(uint32_t k0, uint32_t k1, uint32_t j) {
  uint32_t o0, o1;
  threefry2x32(k0, k1, 0u, j, o0, o1);
  return o0 ^ o1;
}

// bits -> [0,1) float exactly as jax.random.uniform does
__device__ inline float unit_from_bits(uint32_t bits) {
  return __uint_as_float((bits >> 9) | 0x3f800000u) - 1.0f;
}

// XLA's ErfInv32 expansion (Giles polynomial), non-contracted f32 ops.
__device__ inline float xla_erfinv(float x) {
  float w = -log1pf(__fmul_rn(-x, x));
  float p;
  if (w < 5.0f) {
    w = __fadd_rn(w, -2.5f);
    p = 2.81022636e-08f;
    p = __fadd_rn(3.43273939e-07f,  __fmul_rn(p, w));
    p = __fadd_rn(-3.5233877e-06f,  __fmul_rn(p, w));
    p = __fadd_rn(-4.39150654e-06f, __fmul_rn(p, w));
    p = __fadd_rn(0.00021858087f,   __fmul_rn(p, w));
    p = __fadd_rn(-0.00125372503f,  __fmul_rn(p, w));
    p = __fadd_rn(-0.00417768164f,  __fmul_rn(p, w));
    p = __fadd_rn(0.246640727f,     __fmul_rn(p, w));
    p = __fadd_rn(1.50140941f,      __fmul_rn(p, w));
  } else {
    w = __fadd_rn(sqrtf(w), -3.0f);
    p = -0.000200214257f;
    p = __fadd_rn(0.000100950558f,  __fmul_rn(p, w));
    p = __fadd_rn(0.00134934322f,   __fmul_rn(p, w));
    p = __fadd_rn(-0.00367342844f,  __fmul_rn(p, w));
    p = __fadd_rn(0.00573950773f,   __fmul_rn(p, w));
    p = __fadd_rn(-0.0076224613f,   __fmul_rn(p, w));
    p = __fadd_rn(0.00943887047f,   __fmul_rn(p, w));
    p = __fadd_rn(1.00167406f,      __fmul_rn(p, w));
    p = __fadd_rn(2.83297682f,      __fmul_rn(p, w));
  }
  return __fmul_rn(p, x);
}

__device__ inline float normal_from_bits(uint32_t bits) {
  const float lo = -0.99999994f;  // nextafter(-1,0)
  float unit = unit_from_bits(bits);
  float t = __fadd_rn(__fmul_rn(unit, 2.0f), lo);
  t = fmaxf(lo, t);
  return __fmul_rn(1.4142135623730951f, xla_erfinv(t));
}

// Inhibition Euler-Maruyama update — exact round-1 float path, computed
// lazily (candidate lanes + tid0 only).
__device__ inline float compute_ih(const float* __restrict__ inhibition,
                                   int row, float csig,
                                   uint32_t kn0, uint32_t kn1) {
  float nrm = normal_from_bits(random_bits32(kn0, kn1, (uint32_t)row));
  return __fadd_rn(__fmul_rn(0.9f, inhibition[row]), __fmul_rn(csig, nrm));
}

__global__ __launch_bounds__(256, 6) void spike_kernel(
    const float* __restrict__ inputs, const float* __restrict__ inhibition,
    float* __restrict__ out, float csig,
    uint32_t kn0, uint32_t kn1, uint32_t ku0, uint32_t ku1,
    uint32_t kc0, uint32_t kc1) {
  const int row = blockIdx.x;
  const int tid = threadIdx.x;
  const int wid = tid >> 6;
  const float tiny = 1.17549435e-38f;
  const float ln2 = 0.69314718055994531f;
  const float log2e = 1.4426950408889634f;

  // LDS stash for per-element {bits, vhat}; [i8][tid] layout -> stride-256,
  // consecutive lanes hit consecutive banks (conflict-free b32 ops).
  __shared__ uint32_t lbits[8 * 256];
  __shared__ float    lvhat[8 * 256];
  __shared__ double s_sum[4];
  __shared__ float  s_cv[4];
  __shared__ int    s_ci[4];
  __shared__ int    s_final[2];

  // --- issue both global loads up front ---
  const float* rowp = inputs + (size_t)row * N_COLS;
  const float4* rowp4 = reinterpret_cast<const float4*>(rowp);
  float4 a0 = rowp4[tid];
  float4 a1 = rowp4[tid + 256];
  float xv[8] = {a0.x, a0.y, a0.z, a0.w, a1.x, a1.y, a1.z, a1.w};

  // --- phase A: inhibition-free (argmax invariant to uniform -ih shift;
  //     sum rescaled by exp(-ih) later). 2x accumulators for ILP. ---
  float vmaxA = -INFINITY, vmaxB = -INFINITY;
  double tsA = 0.0, tsB = 0.0;
  const uint32_t jbase = (uint32_t)(row * N_COLS + 4 * tid);

#pragma unroll
  for (int i8 = 0; i8 < 8; ++i8) {
    const uint32_t j = jbase + (uint32_t)((i8 & 3) + 1024 * (i8 >> 2));
    uint32_t bits = random_bits32(kc0, kc1, j);
    float u = unit_from_bits(bits);
    float t = __fadd_rn(u, tiny);
    // fast gumbel: 2x v_log_f32 + 2 muls; |fast-exact| <= ~2e-5
    float w = __fmul_rn(-ln2, __log2f(t));
    float g = __fmul_rn(-ln2, __log2f(w));
    float v = __fadd_rn(g, xv[i8]);   // NO ih — uniform shift cancels in argmax
    lbits[i8 * 256 + tid] = bits;
    lvhat[i8 * 256 + tid] = v;
    double e = (double)__builtin_amdgcn_exp2f(__fmul_rn(xv[i8], log2e));
    if (i8 & 1) { vmaxB = fmaxf(vmaxB, v); tsB += e; }
    else        { vmaxA = fmaxf(vmaxA, v); tsA += e; }
  }
  const float tmax = fmaxf(vmaxA, vmaxB);  // per-thread max (phase-B gate)
  float vmax = tmax;
  double tsum = tsA + tsB;

  // --- wave butterfly reduce (all lanes get result) ---
#pragma unroll
  for (int off = 32; off > 0; off >>= 1) {
    tsum += __shfl_xor(tsum, off);
    vmax = fmaxf(vmax, __shfl_xor(vmax, off));
  }
  const float thrM = __fsub_rn(vmax, 1e-3f);  // per-WAVE margin >> fast error

  // --- phase B: exact ocml path only for near-max candidates (~1/wave) ---
  float cval = -INFINITY;
  int   cidx = 0x7fffffff;
  if (tmax >= thrM) {
    float ih = compute_ih(inhibition, row, csig, kn0, kn1);
#pragma unroll
    for (int i8 = 0; i8 < 8; ++i8) {
      float vh = lvhat[i8 * 256 + tid];
      if (vh >= thrM) {
        int col = 4 * tid + 1024 * (i8 >> 2) + (i8 & 3);
        uint32_t bits = lbits[i8 * 256 + tid];
        float t = __fadd_rn(unit_from_bits(bits), tiny);
        float g = -logf(-logf(t));            // exact round-1 float path
        float x = __fsub_rn(rowp[col], ih);   // exact round-1 x
        float v = __fadd_rn(g, x);
        if (v > cval || (v == cval && col < cidx)) { cval = v; cidx = col; }
      }
    }
  }

  // wave butterfly lex-argmax of exact candidates
#pragma unroll
  for (int off = 32; off > 0; off >>= 1) {
    float ov = __shfl_xor(cval, off);
    int   oi = __shfl_xor(cidx, off);
    if (ov > cval || (ov == cval && oi < cidx)) { cval = ov; cidx = oi; }
  }

  // --- single cross-wave combine ---
  if ((tid & 63) == 0) { s_sum[wid] = tsum; s_cv[wid] = cval; s_ci[wid] = cidx; }
  __syncthreads();

  if (tid == 0) {
    double T = s_sum[0] + s_sum[1] + s_sum[2] + s_sum[3];
    float bv = s_cv[0];
    int   bi = s_ci[0];
    for (int w = 1; w < 4; ++w) {
      if (s_cv[w] > bv || (s_cv[w] == bv && s_ci[w] < bi)) { bv = s_cv[w]; bi = s_ci[w]; }
    }
    float ih = compute_ih(inhibition, row, csig, kn0, kn1);
    double total = T * (double)expf(-ih);   // == sum exp(x - ih) to ~1e-7 rel
    float urand = unit_from_bits(random_bits32(ku0, ku1, (uint32_t)row));
    float thr = __fmul_rn(0.001f, (float)total);
    int spike = (urand < thr) ? 1 : 0;
    s_final[0] = bi;
    s_final[1] = spike;
    out[OUT_SPIKES_ELEMS + row] = spike ? __fadd_rn(ih, 5.0f) : ih;
  }
  __syncthreads();

  const int bi = s_final[0];
  const int spike = s_final[1];
  float* orow = out + (size_t)row * N_COLS;
#pragma unroll
  for (int ch = 0; ch < 2; ++ch) {
    const int col = 4 * tid + 1024 * ch;
    float4 z = make_float4(0.f, 0.f, 0.f, 0.f);
    if (spike && bi >= col && bi < col + 4) {
      (&z.x)[bi - col] = 1.0f;
    }
    *reinterpret_cast<float4*>(orow + col) = z;
  }
}

extern "C" void kernel_launch(void* const* d_in, const int* in_sizes, int n_in,
                              void* d_out, int out_size, void* d_ws, size_t ws_size,
                              hipStream_t stream) {
  const float* inputs     = (const float*)d_in[0];
  const float* inhibition = (const float*)d_in[1];
  float* out = (float*)d_out;

  uint32_t kn0, kn1, ku0, ku1, kc0, kc1;
  threefry2x32(0u, 42u, 0u, 0u, kn0, kn1);
  threefry2x32(0u, 42u, 0u, 1u, ku0, ku1);
  threefry2x32(0u, 42u, 0u, 2u, kc0, kc1);

  const float csig = (float)(5.0 * sqrt(0.001));

  dim3 grid(N_ROWS), block(256);
  hipLaunchKernelGGL(spike_kernel, grid, block, 0, stream,
                     inputs, inhibition, out, csig,
                     kn0, kn1, ku0, ku1, kc0, kc1);
}